// Round 6
// baseline (457.416 us; speedup 1.0000x reference)
//
#include <hip/hip_runtime.h>
#include <hip/hip_bf16.h>
#include <math.h>

#define Hh 32
#define Nseq 8192
#define Dh 128
#define NBd 32          // number of 256-row chunks / key blocks
#define BLKSZ 256
#define SAMP 256
#define KVT 512         // block keys + sampled keys per chunk
#define CHK 64          // kv inner chunk
#define NCH 8
#define LOG32 3.4657359027997265f
#define SCALE 0.088388347648318447f
#define SKW 136         // s_k row width: 128 d + 8 pad (272B rows, 16B-aligned)

typedef float f32x4 __attribute__((ext_vector_type(4)));
typedef unsigned ui32x4 __attribute__((ext_vector_type(4)));
typedef __bf16 bf16x8 __attribute__((ext_vector_type(8)));

__device__ __forceinline__ f32x4 mfma16(bf16x8 a, bf16x8 b, f32x4 c) {
  return __builtin_amdgcn_mfma_f32_16x16x32_bf16(a, b, c, 0, 0, 0);
}

__device__ __forceinline__ bf16x8 cvt8(const float* __restrict__ p) {
  float4 a = ((const float4*)p)[0];
  float4 b = ((const float4*)p)[1];
  bf16x8 r;
  r[0] = (__bf16)a.x; r[1] = (__bf16)a.y; r[2] = (__bf16)a.z; r[3] = (__bf16)a.w;
  r[4] = (__bf16)b.x; r[5] = (__bf16)b.y; r[6] = (__bf16)b.z; r[7] = (__bf16)b.w;
  return r;
}

// round pair to bf16, return packed u32 (lo=a, hi=b) + rounded floats
__device__ __forceinline__ unsigned pack2(float a, float b, float& ra, float& rb) {
  __bf16 ba = (__bf16)a, bb = (__bf16)b;
  ra = (float)ba; rb = (float)bb;
  return ((unsigned)__builtin_bit_cast(unsigned short, bb) << 16) |
         (unsigned)__builtin_bit_cast(unsigned short, ba);
}

// ---------------- LSH hash: one thread per row, sequential fp64 ----------------
__global__ __launch_bounds__(256) void lsh_hash_kernel(
    const float* __restrict__ q, const float* __restrict__ k,
    const float* __restrict__ proj, int* __restrict__ buckets) {
  int row = blockIdx.x * 256 + threadIdx.x;          // 0 .. 2*32*8192-1
  const float* x = ((row >> 18) ? k : q) + (size_t)(row & (Hh * Nseq - 1)) * Dh;
  double acc[7] = {0, 0, 0, 0, 0, 0, 0};
#pragma unroll 2
  for (int d0 = 0; d0 < Dh; d0 += 4) {
    float4 xv = *(const float4*)(x + d0);
    double x0 = (double)xv.x, x1 = (double)xv.y, x2 = (double)xv.z, x3 = (double)xv.w;
#pragma unroll
    for (int j = 0; j < 7; j++) {
      acc[j] = fma(x0, (double)proj[(d0 + 0) * 7 + j], acc[j]);
      acc[j] = fma(x1, (double)proj[(d0 + 1) * 7 + j], acc[j]);
      acc[j] = fma(x2, (double)proj[(d0 + 2) * 7 + j], acc[j]);
      acc[j] = fma(x3, (double)proj[(d0 + 3) * 7 + j], acc[j]);
    }
  }
  int bin = 0;
#pragma unroll
  for (int j = 0; j < 7; j++) bin |= (acc[j] > 0.0 ? 1 : 0) << j;
  buckets[row] = bin ^ (bin >> 1);
}

// ---------------- stable counting sort by bucket, per (tensor, head) ----------------
// (known good)
__global__ __launch_bounds__(64) void bucket_sort_kernel(
    const int* __restrict__ buckets, int* __restrict__ idx) {
  __shared__ unsigned hist[64][128];
  int t = threadIdx.x;
  int base = blockIdx.x * Nseq;
  for (int b = 0; b < 128; b++) hist[t][b] = 0;
  __syncthreads();
  for (int i = 0; i < 128; i++) {
    int b = buckets[base + t * 128 + i];
    hist[t][b]++;
  }
  __syncthreads();
  int b0 = 2 * t, b1 = 2 * t + 1;
  unsigned tot0 = 0, tot1 = 0;
  for (int tt = 0; tt < 64; tt++) { unsigned h = hist[tt][b0]; hist[tt][b0] = tot0; tot0 += h; }
  for (int tt = 0; tt < 64; tt++) { unsigned h = hist[tt][b1]; hist[tt][b1] = tot1; tot1 += h; }
  unsigned pair = tot0 + tot1;
  unsigned scan = pair;
  for (int s = 1; s < 64; s <<= 1) {
    unsigned u = __shfl_up(scan, s);
    if (t >= s) scan += u;
  }
  unsigned start0 = scan - pair;      // exclusive prefix over bucket totals
  unsigned start1 = start0 + tot0;
  __syncthreads();
  for (int tt = 0; tt < 64; tt++) { hist[tt][b0] += start0; hist[tt][b1] += start1; }
  __syncthreads();
  for (int i = 0; i < 128; i++) {
    int gi = t * 128 + i;
    int b = buckets[base + gi];
    unsigned pos = hist[t][b]++;
    idx[base + pos] = gi;            // stable: threads cover contiguous in-order chunks
  }
}

// ---------------- fused block-diagonal + residual attention ----------------
// Swapped QK^T: S^T = mfma(K, Q) so each lane holds scores of ONE q-row
// (q = lane&15); softmax reduces with 2 shuffles; P never touches LDS —
// PV A-fragments built in-register via packed-bf16 shuffles.
__global__ __launch_bounds__(512, 4) void hyper_attn_kernel(
    const float* __restrict__ q, const float* __restrict__ k, const float* __restrict__ v,
    const int* __restrict__ sampled, const int* __restrict__ q_idx,
    const int* __restrict__ k_idx, float* __restrict__ out) {
  __shared__ int s_orig[KVT];
  __shared__ __attribute__((aligned(16))) float s_add[KVT];
  __shared__ __attribute__((aligned(16))) __bf16 s_k[CHK][SKW];     // K chunk: row=key, 128 d
  __shared__ __attribute__((aligned(16))) __bf16 s_vt[Dh][72];      // V^T chunk, row=d

  const int c = blockIdx.x, bh = blockIdx.y;
  const int tid = threadIdx.x;
  const int w = tid >> 6, l = tid & 63;
  const int l4 = l >> 4, lm = l & 15;

  // kv list: original rows (via sorted key index) + score addend per column
  {
    int jj = tid;
    if (jj < BLKSZ) {
      s_orig[jj] = k_idx[bh * Nseq + c * BLKSZ + jj];
      s_add[jj] = 0.0f;
    } else {
      int sp = sampled[bh * SAMP + (jj - BLKSZ)];
      s_orig[jj] = k_idx[bh * Nseq + sp];
      s_add[jj] = ((sp >> 8) == c) ? -1e38f : LOG32;
    }
  }

  // Q fragments in registers (serve as MFMA B-operand: B[d][q=lane&15])
  bf16x8 qf[2][4];
  const int* qi = q_idx + bh * Nseq + c * BLKSZ + w * 32;
#pragma unroll
  for (int rt = 0; rt < 2; rt++) {
    int orig = qi[rt * 16 + lm];
    const float* qp = q + ((size_t)bh * Nseq + orig) * Dh + l4 * 8;
#pragma unroll
    for (int dc = 0; dc < 4; dc++) qf[rt][dc] = cvt8(qp + dc * 32);
  }

  f32x4 O[2][8];
  float mrow[2] = {-INFINITY, -INFINITY};
  float lsum[2] = {0.f, 0.f};
#pragma unroll
  for (int rt = 0; rt < 2; rt++)
#pragma unroll
    for (int dt = 0; dt < 8; dt++) { O[rt][dt][0]=0.f; O[rt][dt][1]=0.f; O[rt][dt][2]=0.f; O[rt][dt][3]=0.f; }

  __syncthreads();

  const int laneA = lm + 32 * (l4 & 1);
  const bool hi = (l4 >> 1) & 1;

  for (int ch = 0; ch < NCH; ch++) {
    // stage K (row=key, 128 d): thread t -> key t>>3, d-seg (t&7)*16
    {
      int jk = tid >> 3, pk = tid & 7;
      int origk = s_orig[ch * CHK + jk];
      const float* kp = k + ((size_t)bh * Nseq + origk) * Dh + pk * 16;
      *(bf16x8*)&s_k[jk][pk * 16]     = cvt8(kp);
      *(bf16x8*)&s_k[jk][pk * 16 + 8] = cvt8(kp + 8);
    }
    // stage V^T (row=d): wave w -> d-block w*16, lane l -> key l (conflict-free)
    {
      int origv = s_orig[ch * CHK + l];
      const float* vp = v + ((size_t)bh * Nseq + origv) * Dh + w * 16;
      float4 A = ((const float4*)vp)[0], B = ((const float4*)vp)[1];
      float4 C = ((const float4*)vp)[2], Dv = ((const float4*)vp)[3];
      float tmp[16] = {A.x,A.y,A.z,A.w,B.x,B.y,B.z,B.w,C.x,C.y,C.z,C.w,Dv.x,Dv.y,Dv.z,Dv.w};
#pragma unroll
      for (int dd = 0; dd < 16; dd++) s_vt[w * 16 + dd][l] = (__bf16)tmp[dd];
    }
    __syncthreads();

    // S^T = K·Q^T (+scale +addend): lane holds key = ch*64+ct*16+l4*4+r, q = lm
    float sc[2][4][4];
#pragma unroll
    for (int ct = 0; ct < 4; ct++) {
      f32x4 acc0, acc1;
      acc0[0]=0.f;acc0[1]=0.f;acc0[2]=0.f;acc0[3]=0.f;
      acc1[0]=0.f;acc1[1]=0.f;acc1[2]=0.f;acc1[3]=0.f;
#pragma unroll
      for (int dc = 0; dc < 4; dc++) {
        bf16x8 kf = *(const bf16x8*)&s_k[ct * 16 + lm][dc * 32 + l4 * 8];
        acc0 = mfma16(kf, qf[0][dc], acc0);
        acc1 = mfma16(kf, qf[1][dc], acc1);
      }
      f32x4 addv = *(const f32x4*)&s_add[ch * CHK + ct * 16 + l4 * 4];
#pragma unroll
      for (int r = 0; r < 4; r++) {
        sc[0][ct][r] = acc0[r] * SCALE + addv[r];
        sc[1][ct][r] = acc1[r] * SCALE + addv[r];
      }
    }

    // online softmax per q-row (= lane lm, replicated across l4 groups)
    unsigned q01[2][4], q23[2][4];
#pragma unroll
    for (int rt = 0; rt < 2; rt++) {
      float mc = sc[rt][0][0];
#pragma unroll
      for (int ct = 0; ct < 4; ct++)
#pragma unroll
        for (int r = 0; r < 4; r++) mc = fmaxf(mc, sc[rt][ct][r]);
      mc = fmaxf(mc, __shfl_xor(mc, 16));
      mc = fmaxf(mc, __shfl_xor(mc, 32));
      float mn = fmaxf(mrow[rt], mc);
      float alpha = __expf(mrow[rt] - mn);
      mrow[rt] = mn;
      // rescale O (rows l4*4+r live at lanes 0..15)
      f32x4 aO;
#pragma unroll
      for (int r = 0; r < 4; r++) aO[r] = __shfl(alpha, l4 * 4 + r);
#pragma unroll
      for (int dt = 0; dt < 8; dt++) O[rt][dt] *= aO;
      // P = exp(S - m), rounded to bf16 and packed in-register
      float rsum = 0.f;
#pragma unroll
      for (int ct = 0; ct < 4; ct++) {
        float p0 = __expf(sc[rt][ct][0] - mn);
        float p1 = __expf(sc[rt][ct][1] - mn);
        float p2 = __expf(sc[rt][ct][2] - mn);
        float p3 = __expf(sc[rt][ct][3] - mn);
        float ra, rb, rc, rd;
        q01[rt][ct] = pack2(p0, p1, ra, rb);
        q23[rt][ct] = pack2(p2, p3, rc, rd);
        rsum += (ra + rb) + (rc + rd);
      }
      rsum += __shfl_xor(rsum, 16);
      rsum += __shfl_xor(rsum, 32);
      lsum[rt] = lsum[rt] * alpha + rsum;
    }

    // PV: build A-frag P[q=lm][kc*32+l4*8+j] via packed shuffles, then MFMA
#pragma unroll
    for (int kc = 0; kc < 2; kc++) {
      bf16x8 pa[2];
#pragma unroll
      for (int rt = 0; rt < 2; rt++) {
        unsigned a0 = __shfl((int)q01[rt][2 * kc],     laneA);
        unsigned b0 = __shfl((int)q01[rt][2 * kc + 1], laneA);
        unsigned a1 = __shfl((int)q23[rt][2 * kc],     laneA);
        unsigned b1 = __shfl((int)q23[rt][2 * kc + 1], laneA);
        unsigned a2 = __shfl((int)q01[rt][2 * kc],     laneA + 16);
        unsigned b2 = __shfl((int)q01[rt][2 * kc + 1], laneA + 16);
        unsigned a3 = __shfl((int)q23[rt][2 * kc],     laneA + 16);
        unsigned b3 = __shfl((int)q23[rt][2 * kc + 1], laneA + 16);
        ui32x4 pw;
        pw[0] = hi ? b0 : a0;
        pw[1] = hi ? b1 : a1;
        pw[2] = hi ? b2 : a2;
        pw[3] = hi ? b3 : a3;
        pa[rt] = __builtin_bit_cast(bf16x8, pw);
      }
#pragma unroll
      for (int dt = 0; dt < 8; dt++) {
        bf16x8 vb = *(const bf16x8*)&s_vt[dt * 16 + lm][kc * 32 + l4 * 8];
        O[0][dt] = mfma16(pa[0], vb, O[0][dt]);
        O[1][dt] = mfma16(pa[1], vb, O[1][dt]);
      }
    }
    __syncthreads();
  }

  // epilogue: normalize and scatter to original row order
#pragma unroll
  for (int rt = 0; rt < 2; rt++) {
    float inv = 1.0f / lsum[rt];
    f32x4 invr;
#pragma unroll
    for (int r = 0; r < 4; r++) invr[r] = __shfl(inv, l4 * 4 + r);
    int orow[4];
#pragma unroll
    for (int r = 0; r < 4; r++)
      orow[r] = q_idx[bh * Nseq + c * BLKSZ + w * 32 + rt * 16 + l4 * 4 + r];
#pragma unroll
    for (int r = 0; r < 4; r++) {
      float* op = out + ((size_t)bh * Nseq + orow[r]) * Dh + lm;
#pragma unroll
      for (int dt = 0; dt < 8; dt++) op[dt * 16] = O[rt][dt][r] * invr[r];
    }
  }
}

extern "C" void kernel_launch(void* const* d_in, const int* in_sizes, int n_in,
                              void* d_out, int out_size, void* d_ws, size_t ws_size,
                              hipStream_t stream) {
  const float* q    = (const float*)d_in[0];
  const float* k    = (const float*)d_in[1];
  const float* v    = (const float*)d_in[2];
  const float* proj = (const float*)d_in[3];
  const int* samp   = (const int*)d_in[4];
  float* out = (float*)d_out;

  int* buckets = (int*)d_ws;                   // [2][32][8192]
  int* idx = buckets + 2 * Hh * Nseq;          // [2][32][8192]: q_idx, k_idx

  lsh_hash_kernel<<<(2 * Hh * Nseq) / 256, 256, 0, stream>>>(q, k, proj, buckets);
  bucket_sort_kernel<<<2 * Hh, 64, 0, stream>>>(buckets, idx);
  hyper_attn_kernel<<<dim3(NBd, Hh), 512, 0, stream>>>(
      q, k, v, samp, idx /*q_idx*/, idx + Hh * Nseq /*k_idx*/, out);
}

// Round 7
// 336.623 us; speedup vs baseline: 1.3588x; 1.3588x over previous
//
#include <hip/hip_runtime.h>
#include <hip/hip_bf16.h>
#include <math.h>

#define Hh 32
#define Nseq 8192
#define Dh 128
#define NBd 32          // number of 256-row chunks / key blocks
#define BLKSZ 256
#define SAMP 256
#define KVT 512         // block keys + sampled keys per chunk
#define CHK 64          // kv inner chunk
#define NCH 8
#define LOG32 3.4657359027997265f
#define SCALE 0.088388347648318447f
#define SKW 136         // s_k row width: 128 d + 8 pad (272B rows, 16B-aligned)

typedef float f32x4 __attribute__((ext_vector_type(4)));
typedef unsigned ui32x4 __attribute__((ext_vector_type(4)));
typedef __bf16 bf16x8 __attribute__((ext_vector_type(8)));

__device__ __forceinline__ f32x4 mfma16(bf16x8 a, bf16x8 b, f32x4 c) {
  return __builtin_amdgcn_mfma_f32_16x16x32_bf16(a, b, c, 0, 0, 0);
}

__device__ __forceinline__ bf16x8 cvt8(const float* __restrict__ p) {
  float4 a = ((const float4*)p)[0];
  float4 b = ((const float4*)p)[1];
  bf16x8 r;
  r[0] = (__bf16)a.x; r[1] = (__bf16)a.y; r[2] = (__bf16)a.z; r[3] = (__bf16)a.w;
  r[4] = (__bf16)b.x; r[5] = (__bf16)b.y; r[6] = (__bf16)b.z; r[7] = (__bf16)b.w;
  return r;
}

// round pair to bf16, return packed u32 (lo=a, hi=b) + rounded floats
__device__ __forceinline__ unsigned pack2(float a, float b, float& ra, float& rb) {
  __bf16 ba = (__bf16)a, bb = (__bf16)b;
  ra = (float)ba; rb = (float)bb;
  return ((unsigned)__builtin_bit_cast(unsigned short, bb) << 16) |
         (unsigned)__builtin_bit_cast(unsigned short, ba);
}

// ---------------- LSH hash: one thread per row, sequential fp64 ----------------
__global__ __launch_bounds__(256) void lsh_hash_kernel(
    const float* __restrict__ q, const float* __restrict__ k,
    const float* __restrict__ proj, int* __restrict__ buckets) {
  int row = blockIdx.x * 256 + threadIdx.x;          // 0 .. 2*32*8192-1
  const float* x = ((row >> 18) ? k : q) + (size_t)(row & (Hh * Nseq - 1)) * Dh;
  double acc[7] = {0, 0, 0, 0, 0, 0, 0};
#pragma unroll 2
  for (int d0 = 0; d0 < Dh; d0 += 4) {
    float4 xv = *(const float4*)(x + d0);
    double x0 = (double)xv.x, x1 = (double)xv.y, x2 = (double)xv.z, x3 = (double)xv.w;
#pragma unroll
    for (int j = 0; j < 7; j++) {
      acc[j] = fma(x0, (double)proj[(d0 + 0) * 7 + j], acc[j]);
      acc[j] = fma(x1, (double)proj[(d0 + 1) * 7 + j], acc[j]);
      acc[j] = fma(x2, (double)proj[(d0 + 2) * 7 + j], acc[j]);
      acc[j] = fma(x3, (double)proj[(d0 + 3) * 7 + j], acc[j]);
    }
  }
  int bin = 0;
#pragma unroll
  for (int j = 0; j < 7; j++) bin |= (acc[j] > 0.0 ? 1 : 0) << j;
  buckets[row] = bin ^ (bin >> 1);
}

// ---------------- stable counting sort by bucket, per (tensor, head) ----------------
// (known good)
__global__ __launch_bounds__(64) void bucket_sort_kernel(
    const int* __restrict__ buckets, int* __restrict__ idx) {
  __shared__ unsigned hist[64][128];
  int t = threadIdx.x;
  int base = blockIdx.x * Nseq;
  for (int b = 0; b < 128; b++) hist[t][b] = 0;
  __syncthreads();
  for (int i = 0; i < 128; i++) {
    int b = buckets[base + t * 128 + i];
    hist[t][b]++;
  }
  __syncthreads();
  int b0 = 2 * t, b1 = 2 * t + 1;
  unsigned tot0 = 0, tot1 = 0;
  for (int tt = 0; tt < 64; tt++) { unsigned h = hist[tt][b0]; hist[tt][b0] = tot0; tot0 += h; }
  for (int tt = 0; tt < 64; tt++) { unsigned h = hist[tt][b1]; hist[tt][b1] = tot1; tot1 += h; }
  unsigned pair = tot0 + tot1;
  unsigned scan = pair;
  for (int s = 1; s < 64; s <<= 1) {
    unsigned u = __shfl_up(scan, s);
    if (t >= s) scan += u;
  }
  unsigned start0 = scan - pair;      // exclusive prefix over bucket totals
  unsigned start1 = start0 + tot0;
  __syncthreads();
  for (int tt = 0; tt < 64; tt++) { hist[tt][b0] += start0; hist[tt][b1] += start1; }
  __syncthreads();
  for (int i = 0; i < 128; i++) {
    int gi = t * 128 + i;
    int b = buckets[base + gi];
    unsigned pos = hist[t][b]++;
    idx[base + pos] = gi;            // stable: threads cover contiguous in-order chunks
  }
}

// ---------------- fused block-diagonal + residual attention ----------------
// Swapped QK^T: S^T = mfma(K, Q) so each lane holds scores of ONE q-row
// (q = lane&15); softmax reduces with 2 shuffles; P never touches LDS —
// PV A-fragments built in-register via packed-bf16 shuffles.
// launch_bounds(512,2): cap 256 VGPR — NEVER constrain below the working set
// (R6's (512,4) forced a spill: VGPR 64, FETCH 3.3x, attn 271->348us).
__global__ __launch_bounds__(512, 2) void hyper_attn_kernel(
    const float* __restrict__ q, const float* __restrict__ k, const float* __restrict__ v,
    const int* __restrict__ sampled, const int* __restrict__ q_idx,
    const int* __restrict__ k_idx, float* __restrict__ out) {
  __shared__ int s_orig[KVT];
  __shared__ __attribute__((aligned(16))) float s_add[KVT];
  __shared__ __attribute__((aligned(16))) __bf16 s_k[CHK][SKW];     // K chunk: row=key, 128 d
  __shared__ __attribute__((aligned(16))) __bf16 s_vt[Dh][72];      // V^T chunk, row=d

  const int c = blockIdx.x, bh = blockIdx.y;
  const int tid = threadIdx.x;
  const int w = tid >> 6, l = tid & 63;
  const int l4 = l >> 4, lm = l & 15;

  // kv list: original rows (via sorted key index) + score addend per column
  {
    int jj = tid;
    if (jj < BLKSZ) {
      s_orig[jj] = k_idx[bh * Nseq + c * BLKSZ + jj];
      s_add[jj] = 0.0f;
    } else {
      int sp = sampled[bh * SAMP + (jj - BLKSZ)];
      s_orig[jj] = k_idx[bh * Nseq + sp];
      s_add[jj] = ((sp >> 8) == c) ? -1e38f : LOG32;
    }
  }

  // Q fragments in registers (serve as MFMA B-operand: B[d][q=lane&15])
  bf16x8 qf[2][4];
  const int* qi = q_idx + bh * Nseq + c * BLKSZ + w * 32;
#pragma unroll
  for (int rt = 0; rt < 2; rt++) {
    int orig = qi[rt * 16 + lm];
    const float* qp = q + ((size_t)bh * Nseq + orig) * Dh + l4 * 8;
#pragma unroll
    for (int dc = 0; dc < 4; dc++) qf[rt][dc] = cvt8(qp + dc * 32);
  }

  f32x4 O[2][8];
  float mrow[2] = {-INFINITY, -INFINITY};
  float lsum[2] = {0.f, 0.f};
#pragma unroll
  for (int rt = 0; rt < 2; rt++)
#pragma unroll
    for (int dt = 0; dt < 8; dt++) { O[rt][dt][0]=0.f; O[rt][dt][1]=0.f; O[rt][dt][2]=0.f; O[rt][dt][3]=0.f; }

  __syncthreads();

  const int laneA = lm + 32 * (l4 & 1);
  const bool hi = (l4 >> 1) & 1;

  for (int ch = 0; ch < NCH; ch++) {
    // stage K (row=key, 128 d): thread t -> key t>>3, d-seg (t&7)*16
    {
      int jk = tid >> 3, pk = tid & 7;
      int origk = s_orig[ch * CHK + jk];
      const float* kp = k + ((size_t)bh * Nseq + origk) * Dh + pk * 16;
      *(bf16x8*)&s_k[jk][pk * 16]     = cvt8(kp);
      *(bf16x8*)&s_k[jk][pk * 16 + 8] = cvt8(kp + 8);
    }
    // stage V^T (row=d): wave w -> d-block w*16, lane l -> key l (conflict-free)
    {
      int origv = s_orig[ch * CHK + l];
      const float* vp = v + ((size_t)bh * Nseq + origv) * Dh + w * 16;
      float4 A = ((const float4*)vp)[0], B = ((const float4*)vp)[1];
      float4 C = ((const float4*)vp)[2], Dv = ((const float4*)vp)[3];
      float tmp[16] = {A.x,A.y,A.z,A.w,B.x,B.y,B.z,B.w,C.x,C.y,C.z,C.w,Dv.x,Dv.y,Dv.z,Dv.w};
#pragma unroll
      for (int dd = 0; dd < 16; dd++) s_vt[w * 16 + dd][l] = (__bf16)tmp[dd];
    }
    __syncthreads();

    // S^T = K·Q^T (+scale +addend): lane holds key = ch*64+ct*16+l4*4+r, q = lm
    float sc[2][4][4];
#pragma unroll
    for (int ct = 0; ct < 4; ct++) {
      f32x4 acc0, acc1;
      acc0[0]=0.f;acc0[1]=0.f;acc0[2]=0.f;acc0[3]=0.f;
      acc1[0]=0.f;acc1[1]=0.f;acc1[2]=0.f;acc1[3]=0.f;
#pragma unroll
      for (int dc = 0; dc < 4; dc++) {
        bf16x8 kf = *(const bf16x8*)&s_k[ct * 16 + lm][dc * 32 + l4 * 8];
        acc0 = mfma16(kf, qf[0][dc], acc0);
        acc1 = mfma16(kf, qf[1][dc], acc1);
      }
      f32x4 addv = *(const f32x4*)&s_add[ch * CHK + ct * 16 + l4 * 4];
#pragma unroll
      for (int r = 0; r < 4; r++) {
        sc[0][ct][r] = acc0[r] * SCALE + addv[r];
        sc[1][ct][r] = acc1[r] * SCALE + addv[r];
      }
    }

    // online softmax per q-row (= lane lm, replicated across l4 groups)
    unsigned q01[2][4], q23[2][4];
#pragma unroll
    for (int rt = 0; rt < 2; rt++) {
      float mc = sc[rt][0][0];
#pragma unroll
      for (int ct = 0; ct < 4; ct++)
#pragma unroll
        for (int r = 0; r < 4; r++) mc = fmaxf(mc, sc[rt][ct][r]);
      mc = fmaxf(mc, __shfl_xor(mc, 16));
      mc = fmaxf(mc, __shfl_xor(mc, 32));
      float mn = fmaxf(mrow[rt], mc);
      float alpha = __expf(mrow[rt] - mn);
      mrow[rt] = mn;
      // rescale O (rows l4*4+r live at lanes 0..15)
      f32x4 aO;
#pragma unroll
      for (int r = 0; r < 4; r++) aO[r] = __shfl(alpha, l4 * 4 + r);
#pragma unroll
      for (int dt = 0; dt < 8; dt++) O[rt][dt] *= aO;
      // P = exp(S - m), rounded to bf16 and packed in-register
      float rsum = 0.f;
#pragma unroll
      for (int ct = 0; ct < 4; ct++) {
        float p0 = __expf(sc[rt][ct][0] - mn);
        float p1 = __expf(sc[rt][ct][1] - mn);
        float p2 = __expf(sc[rt][ct][2] - mn);
        float p3 = __expf(sc[rt][ct][3] - mn);
        float ra, rb, rc, rd;
        q01[rt][ct] = pack2(p0, p1, ra, rb);
        q23[rt][ct] = pack2(p2, p3, rc, rd);
        rsum += (ra + rb) + (rc + rd);
      }
      rsum += __shfl_xor(rsum, 16);
      rsum += __shfl_xor(rsum, 32);
      lsum[rt] = lsum[rt] * alpha + rsum;
    }

    // PV: build A-frag P[q=lm][kc*32+l4*8+j] via packed shuffles, then MFMA
#pragma unroll
    for (int kc = 0; kc < 2; kc++) {
      bf16x8 pa[2];
#pragma unroll
      for (int rt = 0; rt < 2; rt++) {
        unsigned a0 = __shfl((int)q01[rt][2 * kc],     laneA);
        unsigned b0 = __shfl((int)q01[rt][2 * kc + 1], laneA);
        unsigned a1 = __shfl((int)q23[rt][2 * kc],     laneA);
        unsigned b1 = __shfl((int)q23[rt][2 * kc + 1], laneA);
        unsigned a2 = __shfl((int)q01[rt][2 * kc],     laneA + 16);
        unsigned b2 = __shfl((int)q01[rt][2 * kc + 1], laneA + 16);
        unsigned a3 = __shfl((int)q23[rt][2 * kc],     laneA + 16);
        unsigned b3 = __shfl((int)q23[rt][2 * kc + 1], laneA + 16);
        ui32x4 pw;
        pw[0] = hi ? b0 : a0;
        pw[1] = hi ? b1 : a1;
        pw[2] = hi ? b2 : a2;
        pw[3] = hi ? b3 : a3;
        pa[rt] = __builtin_bit_cast(bf16x8, pw);
      }
#pragma unroll
      for (int dt = 0; dt < 8; dt++) {
        bf16x8 vb = *(const bf16x8*)&s_vt[dt * 16 + lm][kc * 32 + l4 * 8];
        O[0][dt] = mfma16(pa[0], vb, O[0][dt]);
        O[1][dt] = mfma16(pa[1], vb, O[1][dt]);
      }
    }
    __syncthreads();
  }

  // epilogue: normalize and scatter to original row order
#pragma unroll
  for (int rt = 0; rt < 2; rt++) {
    float inv = 1.0f / lsum[rt];
    f32x4 invr;
#pragma unroll
    for (int r = 0; r < 4; r++) invr[r] = __shfl(inv, l4 * 4 + r);
    int orow[4];
#pragma unroll
    for (int r = 0; r < 4; r++)
      orow[r] = q_idx[bh * Nseq + c * BLKSZ + w * 32 + rt * 16 + l4 * 4 + r];
#pragma unroll
    for (int r = 0; r < 4; r++) {
      float* op = out + ((size_t)bh * Nseq + orow[r]) * Dh + lm;
#pragma unroll
      for (int dt = 0; dt < 8; dt++) op[dt * 16] = O[rt][dt][r] * invr[r];
    }
  }
}

extern "C" void kernel_launch(void* const* d_in, const int* in_sizes, int n_in,
                              void* d_out, int out_size, void* d_ws, size_t ws_size,
                              hipStream_t stream) {
  const float* q    = (const float*)d_in[0];
  const float* k    = (const float*)d_in[1];
  const float* v    = (const float*)d_in[2];
  const float* proj = (const float*)d_in[3];
  const int* samp   = (const int*)d_in[4];
  float* out = (float*)d_out;

  int* buckets = (int*)d_ws;                   // [2][32][8192]
  int* idx = buckets + 2 * Hh * Nseq;          // [2][32][8192]: q_idx, k_idx

  lsh_hash_kernel<<<(2 * Hh * Nseq) / 256, 256, 0, stream>>>(q, k, proj, buckets);
  bucket_sort_kernel<<<2 * Hh, 64, 0, stream>>>(buckets, idx);
  hyper_attn_kernel<<<dim3(NBd, Hh), 512, 0, stream>>>(
      q, k, v, samp, idx /*q_idx*/, idx + Hh * Nseq /*k_idx*/, out);
}

// Round 8
// 274.166 us; speedup vs baseline: 1.6684x; 1.2278x over previous
//
#include <hip/hip_runtime.h>
#include <hip/hip_bf16.h>
#include <math.h>

#define Hh 32
#define Nseq 8192
#define Dh 128
#define NBd 32          // number of 256-row chunks / key blocks
#define BLKSZ 256
#define SAMP 256
#define KVT 512         // block keys + sampled keys per chunk
#define CHK 64          // kv inner chunk
#define NCH 8
#define LOG32 3.4657359027997265f
#define SCALE 0.088388347648318447f
#define SKW 136         // s_k row width: 128 d + 8 pad (272B rows, 16B-aligned)

typedef float f32x4 __attribute__((ext_vector_type(4)));
typedef unsigned ui32x4 __attribute__((ext_vector_type(4)));
typedef __bf16 bf16x8 __attribute__((ext_vector_type(8)));

__device__ __forceinline__ f32x4 mfma16(bf16x8 a, bf16x8 b, f32x4 c) {
  return __builtin_amdgcn_mfma_f32_16x16x32_bf16(a, b, c, 0, 0, 0);
}

__device__ __forceinline__ bf16x8 cvt8(const float* __restrict__ p) {
  float4 a = ((const float4*)p)[0];
  float4 b = ((const float4*)p)[1];
  bf16x8 r;
  r[0] = (__bf16)a.x; r[1] = (__bf16)a.y; r[2] = (__bf16)a.z; r[3] = (__bf16)a.w;
  r[4] = (__bf16)b.x; r[5] = (__bf16)b.y; r[6] = (__bf16)b.z; r[7] = (__bf16)b.w;
  return r;
}

__device__ __forceinline__ bf16x8 cvt8v(float4 a, float4 b) {
  bf16x8 r;
  r[0] = (__bf16)a.x; r[1] = (__bf16)a.y; r[2] = (__bf16)a.z; r[3] = (__bf16)a.w;
  r[4] = (__bf16)b.x; r[5] = (__bf16)b.y; r[6] = (__bf16)b.z; r[7] = (__bf16)b.w;
  return r;
}

// round pair to bf16, return packed u32 (lo=a, hi=b) + rounded floats
__device__ __forceinline__ unsigned pack2(float a, float b, float& ra, float& rb) {
  __bf16 ba = (__bf16)a, bb = (__bf16)b;
  ra = (float)ba; rb = (float)bb;
  return ((unsigned)__builtin_bit_cast(unsigned short, bb) << 16) |
         (unsigned)__builtin_bit_cast(unsigned short, ba);
}

// ---------------- LSH hash: one thread per row, sequential fp64 ----------------
// unroll 8 -> 128B contiguous per-thread bursts (full fetch granularity at
// 512B lane stride). FMA order unchanged vs R7 (bucket bits identical).
__global__ __launch_bounds__(256) void lsh_hash_kernel(
    const float* __restrict__ q, const float* __restrict__ k,
    const float* __restrict__ proj, int* __restrict__ buckets) {
  int row = blockIdx.x * 256 + threadIdx.x;          // 0 .. 2*32*8192-1
  const float* x = ((row >> 18) ? k : q) + (size_t)(row & (Hh * Nseq - 1)) * Dh;
  double acc[7] = {0, 0, 0, 0, 0, 0, 0};
#pragma unroll 8
  for (int d0 = 0; d0 < Dh; d0 += 4) {
    float4 xv = *(const float4*)(x + d0);
    double x0 = (double)xv.x, x1 = (double)xv.y, x2 = (double)xv.z, x3 = (double)xv.w;
#pragma unroll
    for (int j = 0; j < 7; j++) {
      acc[j] = fma(x0, (double)proj[(d0 + 0) * 7 + j], acc[j]);
      acc[j] = fma(x1, (double)proj[(d0 + 1) * 7 + j], acc[j]);
      acc[j] = fma(x2, (double)proj[(d0 + 2) * 7 + j], acc[j]);
      acc[j] = fma(x3, (double)proj[(d0 + 3) * 7 + j], acc[j]);
    }
  }
  int bin = 0;
#pragma unroll
  for (int j = 0; j < 7; j++) bin |= (acc[j] > 0.0 ? 1 : 0) << j;
  buckets[row] = bin ^ (bin >> 1);
}

// ---------------- stable counting sort by bucket, per (tensor, head) ----------------
// (known good)
__global__ __launch_bounds__(64) void bucket_sort_kernel(
    const int* __restrict__ buckets, int* __restrict__ idx) {
  __shared__ unsigned hist[64][128];
  int t = threadIdx.x;
  int base = blockIdx.x * Nseq;
  for (int b = 0; b < 128; b++) hist[t][b] = 0;
  __syncthreads();
  for (int i = 0; i < 128; i++) {
    int b = buckets[base + t * 128 + i];
    hist[t][b]++;
  }
  __syncthreads();
  int b0 = 2 * t, b1 = 2 * t + 1;
  unsigned tot0 = 0, tot1 = 0;
  for (int tt = 0; tt < 64; tt++) { unsigned h = hist[tt][b0]; hist[tt][b0] = tot0; tot0 += h; }
  for (int tt = 0; tt < 64; tt++) { unsigned h = hist[tt][b1]; hist[tt][b1] = tot1; tot1 += h; }
  unsigned pair = tot0 + tot1;
  unsigned scan = pair;
  for (int s = 1; s < 64; s <<= 1) {
    unsigned u = __shfl_up(scan, s);
    if (t >= s) scan += u;
  }
  unsigned start0 = scan - pair;      // exclusive prefix over bucket totals
  unsigned start1 = start0 + tot0;
  __syncthreads();
  for (int tt = 0; tt < 64; tt++) { hist[tt][b0] += start0; hist[tt][b1] += start1; }
  __syncthreads();
  for (int i = 0; i < 128; i++) {
    int gi = t * 128 + i;
    int b = buckets[base + gi];
    unsigned pos = hist[t][b]++;
    idx[base + pos] = gi;            // stable: threads cover contiguous in-order chunks
  }
}

// ---------------- fused block-diagonal + residual attention ----------------
// Swapped QK^T (S^T = mfma(K,Q), lane owns one q-row), in-register P.
// Double-buffered K/V staging with reg-prefetch: one barrier per chunk;
// next chunk's HBM latency hides under QK+softmax, ds_write under PV.
__global__ __launch_bounds__(512, 2) void hyper_attn_kernel(
    const float* __restrict__ q, const float* __restrict__ k, const float* __restrict__ v,
    const int* __restrict__ sampled, const int* __restrict__ q_idx,
    const int* __restrict__ k_idx, float* __restrict__ out) {
  __shared__ int s_orig[KVT];
  __shared__ __attribute__((aligned(16))) float s_add[KVT];
  __shared__ __attribute__((aligned(16))) __bf16 s_k[2][CHK][SKW];  // K: row=key, 128 d
  __shared__ __attribute__((aligned(16))) __bf16 s_vt[2][Dh][72];   // V^T: row=d

  const int c = blockIdx.x, bh = blockIdx.y;
  const int tid = threadIdx.x;
  const int w = tid >> 6, l = tid & 63;
  const int l4 = l >> 4, lm = l & 15;
  const int jk = tid >> 3, pk = tid & 7;      // K-staging owner: key jk, d-seg pk*16

  // kv list: original rows (via sorted key index) + score addend per column
  {
    int jj = tid;
    if (jj < BLKSZ) {
      s_orig[jj] = k_idx[bh * Nseq + c * BLKSZ + jj];
      s_add[jj] = 0.0f;
    } else {
      int sp = sampled[bh * SAMP + (jj - BLKSZ)];
      s_orig[jj] = k_idx[bh * Nseq + sp];
      s_add[jj] = ((sp >> 8) == c) ? -1e38f : LOG32;
    }
  }

  // Q fragments in registers (MFMA B-operand: B[d][q=lane&15])
  bf16x8 qf[2][4];
  const int* qi = q_idx + bh * Nseq + c * BLKSZ + w * 32;
#pragma unroll
  for (int rt = 0; rt < 2; rt++) {
    int orig = qi[rt * 16 + lm];
    const float* qp = q + ((size_t)bh * Nseq + orig) * Dh + l4 * 8;
#pragma unroll
    for (int dc = 0; dc < 4; dc++) qf[rt][dc] = cvt8(qp + dc * 32);
  }

  f32x4 O[2][8];
  float mrow[2] = {-INFINITY, -INFINITY};
  float lsum[2] = {0.f, 0.f};
#pragma unroll
  for (int rt = 0; rt < 2; rt++)
#pragma unroll
    for (int dt = 0; dt < 8; dt++) { O[rt][dt][0]=0.f; O[rt][dt][1]=0.f; O[rt][dt][2]=0.f; O[rt][dt][3]=0.f; }

  __syncthreads();

  // prologue: stage chunk 0 into buffer 0
  {
    int origk = s_orig[jk];
    const float* kp = k + ((size_t)bh * Nseq + origk) * Dh + pk * 16;
    *(bf16x8*)&s_k[0][jk][pk * 16]     = cvt8(kp);
    *(bf16x8*)&s_k[0][jk][pk * 16 + 8] = cvt8(kp + 8);
    int origv = s_orig[l];
    const float* vp = v + ((size_t)bh * Nseq + origv) * Dh + w * 16;
    float4 A = ((const float4*)vp)[0], B = ((const float4*)vp)[1];
    float4 C = ((const float4*)vp)[2], Dv = ((const float4*)vp)[3];
    float tmp[16] = {A.x,A.y,A.z,A.w,B.x,B.y,B.z,B.w,C.x,C.y,C.z,C.w,Dv.x,Dv.y,Dv.z,Dv.w};
#pragma unroll
    for (int dd = 0; dd < 16; dd++) s_vt[0][w * 16 + dd][l] = (__bf16)tmp[dd];
  }
  __syncthreads();

  const int laneA = lm + 32 * (l4 & 1);
  const bool hi = (l4 >> 1) & 1;

  for (int ch = 0; ch < NCH; ch++) {
    const int cur = ch & 1;
    const bool pf = (ch + 1 < NCH);

    // issue next-chunk global loads (latency hides under QK+softmax)
    float4 kA, kB, kC, kD, vA, vB, vC, vD;
    if (pf) {
      int origk = s_orig[(ch + 1) * CHK + jk];
      const float4* kp = (const float4*)(k + ((size_t)bh * Nseq + origk) * Dh + pk * 16);
      kA = kp[0]; kB = kp[1]; kC = kp[2]; kD = kp[3];
      int origv = s_orig[(ch + 1) * CHK + l];
      const float4* vp = (const float4*)(v + ((size_t)bh * Nseq + origv) * Dh + w * 16);
      vA = vp[0]; vB = vp[1]; vC = vp[2]; vD = vp[3];
    }

    // S^T = K·Q^T (+scale +addend): lane holds key = ch*64+ct*16+l4*4+r, q = lm
    float sc[2][4][4];
#pragma unroll
    for (int ct = 0; ct < 4; ct++) {
      f32x4 acc0, acc1;
      acc0[0]=0.f;acc0[1]=0.f;acc0[2]=0.f;acc0[3]=0.f;
      acc1[0]=0.f;acc1[1]=0.f;acc1[2]=0.f;acc1[3]=0.f;
#pragma unroll
      for (int dc = 0; dc < 4; dc++) {
        bf16x8 kf = *(const bf16x8*)&s_k[cur][ct * 16 + lm][dc * 32 + l4 * 8];
        acc0 = mfma16(kf, qf[0][dc], acc0);
        acc1 = mfma16(kf, qf[1][dc], acc1);
      }
      f32x4 addv = *(const f32x4*)&s_add[ch * CHK + ct * 16 + l4 * 4];
#pragma unroll
      for (int r = 0; r < 4; r++) {
        sc[0][ct][r] = acc0[r] * SCALE + addv[r];
        sc[1][ct][r] = acc1[r] * SCALE + addv[r];
      }
    }

    // online softmax per q-row (= lane lm, replicated across l4 groups)
    unsigned q01[2][4], q23[2][4];
#pragma unroll
    for (int rt = 0; rt < 2; rt++) {
      float mc = sc[rt][0][0];
#pragma unroll
      for (int ct = 0; ct < 4; ct++)
#pragma unroll
        for (int r = 0; r < 4; r++) mc = fmaxf(mc, sc[rt][ct][r]);
      mc = fmaxf(mc, __shfl_xor(mc, 16));
      mc = fmaxf(mc, __shfl_xor(mc, 32));
      float mn = fmaxf(mrow[rt], mc);
      float alpha = __expf(mrow[rt] - mn);
      mrow[rt] = mn;
      f32x4 aO;
#pragma unroll
      for (int r = 0; r < 4; r++) aO[r] = __shfl(alpha, l4 * 4 + r);
#pragma unroll
      for (int dt = 0; dt < 8; dt++) O[rt][dt] *= aO;
      float rsum = 0.f;
#pragma unroll
      for (int ct = 0; ct < 4; ct++) {
        float p0 = __expf(sc[rt][ct][0] - mn);
        float p1 = __expf(sc[rt][ct][1] - mn);
        float p2 = __expf(sc[rt][ct][2] - mn);
        float p3 = __expf(sc[rt][ct][3] - mn);
        float ra, rb, rc, rd;
        q01[rt][ct] = pack2(p0, p1, ra, rb);
        q23[rt][ct] = pack2(p2, p3, rc, rd);
        rsum += (ra + rb) + (rc + rd);
      }
      rsum += __shfl_xor(rsum, 16);
      rsum += __shfl_xor(rsum, 32);
      lsum[rt] = lsum[rt] * alpha + rsum;
    }

    // write staged chunk ch+1 into buffer cur^1 (readers of cur^1's old data
    // finished before the barrier that started this iteration)
    if (pf) {
      *(bf16x8*)&s_k[cur ^ 1][jk][pk * 16]     = cvt8v(kA, kB);
      *(bf16x8*)&s_k[cur ^ 1][jk][pk * 16 + 8] = cvt8v(kC, kD);
      float tmp[16] = {vA.x,vA.y,vA.z,vA.w,vB.x,vB.y,vB.z,vB.w,
                       vC.x,vC.y,vC.z,vC.w,vD.x,vD.y,vD.z,vD.w};
#pragma unroll
      for (int dd = 0; dd < 16; dd++) s_vt[cur ^ 1][w * 16 + dd][l] = (__bf16)tmp[dd];
    }

    // PV: build A-frag P[q=lm][kc*32+l4*8+j] via packed shuffles, then MFMA
#pragma unroll
    for (int kc = 0; kc < 2; kc++) {
      bf16x8 pa[2];
#pragma unroll
      for (int rt = 0; rt < 2; rt++) {
        unsigned a0 = __shfl((int)q01[rt][2 * kc],     laneA);
        unsigned b0 = __shfl((int)q01[rt][2 * kc + 1], laneA);
        unsigned a1 = __shfl((int)q23[rt][2 * kc],     laneA);
        unsigned b1 = __shfl((int)q23[rt][2 * kc + 1], laneA);
        unsigned a2 = __shfl((int)q01[rt][2 * kc],     laneA + 16);
        unsigned b2 = __shfl((int)q01[rt][2 * kc + 1], laneA + 16);
        unsigned a3 = __shfl((int)q23[rt][2 * kc],     laneA + 16);
        unsigned b3 = __shfl((int)q23[rt][2 * kc + 1], laneA + 16);
        ui32x4 pw;
        pw[0] = hi ? b0 : a0;
        pw[1] = hi ? b1 : a1;
        pw[2] = hi ? b2 : a2;
        pw[3] = hi ? b3 : a3;
        pa[rt] = __builtin_bit_cast(bf16x8, pw);
      }
#pragma unroll
      for (int dt = 0; dt < 8; dt++) {
        bf16x8 vb = *(const bf16x8*)&s_vt[cur][dt * 16 + lm][kc * 32 + l4 * 8];
        O[0][dt] = mfma16(pa[0], vb, O[0][dt]);
        O[1][dt] = mfma16(pa[1], vb, O[1][dt]);
      }
    }
    __syncthreads();      // single barrier per chunk
  }

  // epilogue: normalize and scatter to original row order
#pragma unroll
  for (int rt = 0; rt < 2; rt++) {
    float inv = 1.0f / lsum[rt];
    f32x4 invr;
#pragma unroll
    for (int r = 0; r < 4; r++) invr[r] = __shfl(inv, l4 * 4 + r);
    int orow[4];
#pragma unroll
    for (int r = 0; r < 4; r++)
      orow[r] = q_idx[bh * Nseq + c * BLKSZ + w * 32 + rt * 16 + l4 * 4 + r];
#pragma unroll
    for (int r = 0; r < 4; r++) {
      float* op = out + ((size_t)bh * Nseq + orow[r]) * Dh + lm;
#pragma unroll
      for (int dt = 0; dt < 8; dt++) op[dt * 16] = O[rt][dt][r] * invr[r];
    }
  }
}

extern "C" void kernel_launch(void* const* d_in, const int* in_sizes, int n_in,
                              void* d_out, int out_size, void* d_ws, size_t ws_size,
                              hipStream_t stream) {
  const float* q    = (const float*)d_in[0];
  const float* k    = (const float*)d_in[1];
  const float* v    = (const float*)d_in[2];
  const float* proj = (const float*)d_in[3];
  const int* samp   = (const int*)d_in[4];
  float* out = (float*)d_out;

  int* buckets = (int*)d_ws;                   // [2][32][8192]
  int* idx = buckets + 2 * Hh * Nseq;          // [2][32][8192]: q_idx, k_idx

  lsh_hash_kernel<<<(2 * Hh * Nseq) / 256, 256, 0, stream>>>(q, k, proj, buckets);
  bucket_sort_kernel<<<2 * Hh, 64, 0, stream>>>(buckets, idx);
  hyper_attn_kernel<<<dim3(NBd, Hh), 512, 0, stream>>>(
      q, k, v, samp, idx /*q_idx*/, idx + Hh * Nseq /*k_idx*/, out);
}